// Round 6
// baseline (914.050 us; speedup 1.0000x reference)
//
#include <hip/hip_runtime.h>
#include <hip/hip_bf16.h>
#include <stdint.h>

#define DEV __device__ __forceinline__

typedef short s16x8 __attribute__((ext_vector_type(8)));
typedef float f32x4 __attribute__((ext_vector_type(4)));
typedef int i32x4 __attribute__((ext_vector_type(4)));

// async 16B global->LDS. LDS side is wave-uniform base + lane*16 (HW rule).
DEV void async_load16(const void* g, void* l) {
  __builtin_amdgcn_global_load_lds((void __attribute__((address_space(1)))*)(g),
                                   (void __attribute__((address_space(3)))*)(l),
                                   16, 0, 0);
}

DEV unsigned pack_bf16x2(float a, float b) {
  __hip_bfloat162 h = __float22bfloat162_rn(make_float2(a, b));
  union { __hip_bfloat162 h2; unsigned u; } cv;
  cv.h2 = h;
  return cv.u;
}

// ---------------- cast x fp32 -> bf16 ----------------
__global__ __launch_bounds__(256) void cast_x_kernel(const float* __restrict__ in,
                                                     __hip_bfloat16* __restrict__ out, int n4) {
  int i = blockIdx.x * 256 + threadIdx.x;
  if (i >= n4) return;
  float4 v = ((const float4*)in)[i];
  alignas(8) __hip_bfloat16 t[4] = {__float2bfloat16(v.x), __float2bfloat16(v.y),
                                    __float2bfloat16(v.z), __float2bfloat16(v.w)};
  *(uint2*)(out + (size_t)i * 4) = *(const uint2*)t;
}

// ------- transpose-cast: dst[b][c][r] = src[b][r][c] * scale  (bf16 out) -------
// used for Wo (R=C=1024, 256 tiles, scale 1)
__global__ __launch_bounds__(256) void transpose_cast_kernel(const float* __restrict__ src,
                                                             __hip_bfloat16* __restrict__ dst,
                                                             int R, int C, float scale) {
  __shared__ float tile[64][65];
  const int r0 = blockIdx.x * 64, c0 = blockIdx.y * 64, bt = blockIdx.z;
  const int tc = threadIdx.x & 63, tr = threadIdx.x >> 6;
  const float* sp = src + (size_t)bt * R * C;
#pragma unroll
  for (int rr = 0; rr < 64; rr += 4)
    tile[tr + rr][tc] = sp[(size_t)(r0 + tr + rr) * C + c0 + tc];
  __syncthreads();
  __hip_bfloat16* dp = dst + (size_t)bt * R * C;
#pragma unroll
  for (int rr = 0; rr < 64; rr += 4) {
    int cc = tr + rr;
    dp[(size_t)(c0 + cc) * R + r0 + tc] = __float2bfloat16(tile[tc][cc] * scale);
  }
}

// ------- fused Wq/Wk/Wv transpose-cast (R=1024, C=64, 16 heads each) -------
// z = 0..47: which = z>>4 (0=Wq,1=Wk,2=Wv), head = z&15. Wq scaled.
__global__ __launch_bounds__(256) void qkv_transpose_kernel(const float* __restrict__ Wq,
                                                            const float* __restrict__ Wk,
                                                            const float* __restrict__ Wv,
                                                            __hip_bfloat16* __restrict__ dst,
                                                            float qscale) {
  __shared__ float tile[64][65];
  const int z = blockIdx.z, which = z >> 4, bt = z & 15;
  const int r0 = blockIdx.x * 64;
  const int tc = threadIdx.x & 63, tr = threadIdx.x >> 6;
  const float* src = (which == 0) ? Wq : (which == 1) ? Wk : Wv;
  const float scale = (which == 0) ? qscale : 1.0f;
  const float* sp = src + (size_t)bt * 1024 * 64;
#pragma unroll
  for (int rr = 0; rr < 64; rr += 4)
    tile[tr + rr][tc] = sp[(size_t)(r0 + tr + rr) * 64 + tc];
  __syncthreads();
  __hip_bfloat16* dp = dst + (size_t)z * 1024 * 64;
#pragma unroll
  for (int rr = 0; rr < 64; rr += 4) {
    int cc = tr + rr;
    dp[(size_t)(cc)*1024 + r0 + tc] = __float2bfloat16(tile[tc][cc] * scale);
  }
}

// ---------------- 128x128 bf16 MFMA GEMM, BK=32, m97 structure ----------------
// C[M,N] = A[M,K] * Bt[N,K]^T.
// MODE 0 (fused QKV, N=3072): cols <1024 -> Q [B,H,S,DH] (out0), <2048 -> K (out1),
//                             >=2048 -> Vt [B,DHg,S] packed-transposed store (out2)
// MODE 2: fp32 out0 = acc + bias[col] + resid[row*1024+col]
template <int MODE>
__global__ __launch_bounds__(256) void gemm128(const __hip_bfloat16* __restrict__ A,
                                               const __hip_bfloat16* __restrict__ Bt,
                                               void* __restrict__ out0,
                                               void* __restrict__ out1,
                                               void* __restrict__ out2,
                                               const float* __restrict__ bias,
                                               const float* __restrict__ resid,
                                               int M, int N, int K) {
  __shared__ __hip_bfloat16 As[128 * 32];
  __shared__ __hip_bfloat16 Bs[128 * 32];
  const int tid = threadIdx.x;
  const int lane = tid & 63, w = tid >> 6;
  const int lr = lane & 15, lq = lane >> 4;
  const int wm = w >> 1, wn = w & 1;
  const int m0 = blockIdx.y * 128, n0 = blockIdx.x * 128;

  const f32x4 fz = {0.f, 0.f, 0.f, 0.f};
  f32x4 acc[4][4];
#pragma unroll
  for (int i = 0; i < 4; i++)
#pragma unroll
    for (int j = 0; j < 4; j++) acc[i][j] = fz;

  const int kiters = K >> 5;
  for (int kt = 0; kt < kiters; kt++) {
    __syncthreads();
#pragma unroll
    for (int r = 0; r < 2; r++) {
      const int c = r * 256 + tid;
      const int row = c >> 2, kc = c & 3;
      async_load16((const short*)A + (size_t)(m0 + row) * K + kt * 32 + kc * 8,
                   (char*)As + (r * 256 + (tid & 0xC0)) * 16);
      async_load16((const short*)Bt + (size_t)(n0 + row) * K + kt * 32 + kc * 8,
                   (char*)Bs + (r * 256 + (tid & 0xC0)) * 16);
    }
    __syncthreads();
    const short* Ap = (const short*)As;
    const short* Bp = (const short*)Bs;
    s16x8 av[4], bv[4];
#pragma unroll
    for (int i = 0; i < 4; i++)
      av[i] = *(const s16x8*)(Ap + (wm * 64 + i * 16 + lr) * 32 + lq * 8);
#pragma unroll
    for (int j = 0; j < 4; j++)
      bv[j] = *(const s16x8*)(Bp + (wn * 64 + j * 16 + lr) * 32 + lq * 8);
#pragma unroll
    for (int i = 0; i < 4; i++)
#pragma unroll
      for (int j = 0; j < 4; j++)
        acc[i][j] = __builtin_amdgcn_mfma_f32_16x16x32_bf16(av[i], bv[j], acc[i][j], 0, 0, 0);
  }

  if constexpr (MODE == 0) {
    if (n0 < 2048) {
      __hip_bfloat16* dst01 = (__hip_bfloat16*)((n0 < 1024) ? out0 : out1);
#pragma unroll
      for (int i = 0; i < 4; i++)
#pragma unroll
        for (int j = 0; j < 4; j++)
#pragma unroll
          for (int r = 0; r < 4; r++) {
            const int row = m0 + wm * 64 + i * 16 + lq * 4 + r;
            const int col = n0 + wn * 64 + j * 16 + lr;
            const int bb = row >> 11, s = row & 2047;
            const int colq = col & 1023;
            dst01[((((size_t)bb * 16 + (colq >> 6)) * 2048 + s) << 6) + (col & 63)] =
                __float2bfloat16(acc[i][j][r]);
          }
    } else {
      // V block: packed-transpose store to Vt[b][dhg][s] (4 consecutive s per lane)
#pragma unroll
      for (int i = 0; i < 4; i++)
#pragma unroll
        for (int j = 0; j < 4; j++) {
          const int row0 = m0 + wm * 64 + i * 16 + lq * 4;
          const int col = (n0 - 2048) + wn * 64 + j * 16 + lr;  // dh-global 0..1023
          const int bb = row0 >> 11, s0 = row0 & 2047;
          alignas(8) __hip_bfloat16 t4[4] = {
              __float2bfloat16(acc[i][j][0]), __float2bfloat16(acc[i][j][1]),
              __float2bfloat16(acc[i][j][2]), __float2bfloat16(acc[i][j][3])};
          *(uint2*)((__hip_bfloat16*)out2 + (size_t)bb * 2097152 + (size_t)col * 2048 + s0) =
              *(const uint2*)t4;
        }
    }
  } else {
#pragma unroll
    for (int i = 0; i < 4; i++)
#pragma unroll
      for (int j = 0; j < 4; j++)
#pragma unroll
        for (int r = 0; r < 4; r++) {
          const int row = m0 + wm * 64 + i * 16 + lq * 4 + r;
          const int col = n0 + wn * 64 + j * 16 + lr;
          const size_t idx = (size_t)row * 1024 + col;
          ((float*)out0)[idx] = acc[i][j][r] + bias[col] + resid[idx];
        }
  }
}

// ------------- streaming-softmax attention: 2-wave blocks, 64 q/wave -------------
// Q [B,H,S,64] pre-scaled by 0.125*log2(e) -> log2-domain scores, exp2 softmax.
// K [B,H,S,64], Vt [B,H,64,S] -> concat out [B,S,1024].
// Block = 128 threads (2 waves), q-tile 128 (each wave: same... no — wave w owns
// the w-th 32-kv half of each staged 64-kv tile for ALL 64 q of the block? q-tile
// is 64 q total; both waves cover the same 64 q, wave w handles kv half w.
// nt=4 (64 q/wave) -> 8 ds_read_b128 feed 32 MFMAs (0.25 reads/MFMA, half of R4).
// LDS: K 8KB + V 8KB staging; epilogue reuses it for one lane-linear f32x4
// exchange (zero bank conflicts by construction) + both waves store in parallel.
// Grid x=hb: XCD = blockid%8 = hb%8 -> all 32 qt of one (b,h) share K/V in one L2.
__global__ __launch_bounds__(128, 3) void flash_kernel(const __hip_bfloat16* __restrict__ Qg,
                                                       const __hip_bfloat16* __restrict__ Kg,
                                                       const __hip_bfloat16* __restrict__ Vtg,
                                                       __hip_bfloat16* __restrict__ Og) {
  __shared__ alignas(16) char smem[16896];  // staging 16KB; epilogue xch 16KB + lx 512B
  __hip_bfloat16* Klds = (__hip_bfloat16*)smem;           // [64 kv][64 d] chunks xor (kv&7)
  __hip_bfloat16* Vlds = (__hip_bfloat16*)(smem + 8192);  // [64 dh][64 kv] chunks xor (dh&7)
  float* xch = (float*)smem;                              // 2 slots x 2048 f32
  float* lx = (float*)(smem + 16384);                     // [2][32]
  const int tid = threadIdx.x;
  const int lane = tid & 63, w = tid >> 6;
  const int lr = lane & 15, lq = lane >> 4;
  const int hb = blockIdx.x, qt = blockIdx.y;
  const int h = hb >> 2, b = hb & 3;
  const size_t bh = (size_t)b * 16 + h;
  const short* Qbase = (const short*)Qg + (bh * 2048 + (size_t)qt * 64) * 64;
  const short* Kbh = (const short*)Kg + bh * 2048 * 64;
  const short* Vbh = (const short*)Vtg + bh * 64 * 2048;

  // tile-row->kv permutation pieces (in-lane P trick); gk = lr&7 (lane-constant)
  const int rbase = (lr >> 2) * 8 + (lr & 3);
  const int gk = lr & 7;

  // Q as B-operand fragments: wave holds all 64 q rows of the block (4 n-tiles)
  s16x8 qb[4][2];
#pragma unroll
  for (int nt = 0; nt < 4; nt++)
#pragma unroll
    for (int ks = 0; ks < 2; ks++)
      qb[nt][ks] = *(const s16x8*)(Qbase + (nt * 16 + lr) * 64 + ks * 32 + lq * 8);

  const f32x4 fz = {0.f, 0.f, 0.f, 0.f};
  f32x4 o[4][4];  // [q n-tile][dh n-tile] -- partial over this wave's kv halves
#pragma unroll
  for (int i = 0; i < 4; i++)
#pragma unroll
    for (int j = 0; j < 4; j++) o[i][j] = fz;
  float lsum[4] = {0.f, 0.f, 0.f, 0.f};

  for (int kb = 0; kb < 32; kb++) {  // 64-kv tiles
    __syncthreads();
    const short* Ksrc = Kbh + kb * 64 * 64;
#pragma unroll
    for (int r = 0; r < 4; r++) {  // K tile: 64 rows x 128B, chunk xor (row&7)... g(row)
      int c = r * 128 + tid;
      int row = c >> 3, ck = c & 7;
      int g = (row & 3) | (((row >> 3) & 1) << 2);
      async_load16(Ksrc + row * 64 + (ck ^ g) * 8,
                   (char*)Klds + (r * 128 + (tid & 64)) * 16);
    }
#pragma unroll
    for (int r = 0; r < 4; r++) {  // Vt tile: 64 rows x 128B, chunk xor (row&7)
      int c = r * 128 + tid;
      int row = c >> 3, ck = c & 7;
      async_load16(Vbh + (size_t)row * 2048 + kb * 64 + ((ck ^ (row & 7))) * 8,
                   (char*)Vlds + (r * 128 + (tid & 64)) * 16);
    }
    __syncthreads();

    const short* Kp = (const short*)Klds;
    const short* Vp = (const short*)Vlds;

    // this wave's 32-kv half; S^T = K*Q^T, P built in-lane
    union { i32x4 i; s16x8 s; } pa[4];
#pragma unroll
    for (int mt = 0; mt < 2; mt++) {
      const int kvrow = w * 32 + mt * 4 + rbase;
      s16x8 kf0 = *(const s16x8*)(Kp + kvrow * 64 + (((0 * 4 + lq) ^ gk)) * 8);
      s16x8 kf1 = *(const s16x8*)(Kp + kvrow * 64 + (((1 * 4 + lq) ^ gk)) * 8);
#pragma unroll
      for (int nt = 0; nt < 4; nt++) {
        f32x4 st = fz;
        st = __builtin_amdgcn_mfma_f32_16x16x32_bf16(kf0, qb[nt][0], st, 0, 0, 0);
        st = __builtin_amdgcn_mfma_f32_16x16x32_bf16(kf1, qb[nt][1], st, 0, 0, 0);
        float e0 = __builtin_amdgcn_exp2f(st[0]);
        float e1 = __builtin_amdgcn_exp2f(st[1]);
        float e2 = __builtin_amdgcn_exp2f(st[2]);
        float e3 = __builtin_amdgcn_exp2f(st[3]);
        lsum[nt] += (e0 + e1) + (e2 + e3);
        pa[nt].i[mt * 2 + 0] = (int)pack_bf16x2(e0, e1);
        pa[nt].i[mt * 2 + 1] = (int)pack_bf16x2(e2, e3);
      }
    }
#pragma unroll
    for (int ndh = 0; ndh < 4; ndh++) {
      int vrow = ndh * 16 + lr;
      s16x8 vb = *(const s16x8*)(Vp + vrow * 64 + (((w * 4 + lq) ^ (vrow & 7))) * 8);
#pragma unroll
      for (int nt = 0; nt < 4; nt++)
        o[nt][ndh] = __builtin_amdgcn_mfma_f32_16x16x32_bf16(pa[nt].s, vb, o[nt][ndh], 0, 0, 0);
    }
  }

  // quad-reduce lsum: every lane holds its wave's l(q = nt*16 + lr)
#pragma unroll
  for (int nt = 0; nt < 4; nt++) {
    lsum[nt] += __shfl_xor(lsum[nt], 16);
    lsum[nt] += __shfl_xor(lsum[nt], 32);
  }

  // ---- single lane-linear exchange between the 2 waves ----
  // wave w outputs q-half nt in {2w, 2w+1}; it ships the other half.
  __syncthreads();
#pragma unroll
  for (int ntr = 0; ntr < 2; ntr++) {
    const int nt_write = 2 * (1 - w) + ntr;
#pragma unroll
    for (int ndh = 0; ndh < 4; ndh++)
      *(f32x4*)(xch + w * 2048 + (ntr * 4 + ndh) * 256 + lane * 4) = o[nt_write][ndh];
    if (lq == 0) lx[w * 32 + ntr * 16 + lr] = lsum[nt_write];
  }
  __syncthreads();
#pragma unroll
  for (int ntr = 0; ntr < 2; ntr++) {
    const int nt = 2 * w + ntr;
#pragma unroll
    for (int ndh = 0; ndh < 4; ndh++) {
      f32x4 add = *(const f32x4*)(xch + (1 - w) * 2048 + (ntr * 4 + ndh) * 256 + lane * 4);
      o[nt][ndh] += add;
    }
    lsum[nt] += lx[(1 - w) * 32 + ntr * 16 + lr];
  }

  // normalize + write concat [B,S,1024] (both waves in parallel, own q-half)
#pragma unroll
  for (int ntr = 0; ntr < 2; ntr++) {
    const int nt = 2 * w + ntr;
#pragma unroll
    for (int r = 0; r < 4; r++) {
      float lv = __shfl(lsum[nt], lq * 4 + r);  // lane lr = q&15, quad 0
      float inv = __builtin_amdgcn_rcpf(lv);
      int rowg = qt * 64 + nt * 16 + lq * 4 + r;
#pragma unroll
      for (int ndh = 0; ndh < 4; ndh++) {
        Og[((size_t)b * 2048 + rowg) * 1024 + h * 64 + ndh * 16 + lr] =
            __float2bfloat16(o[nt][ndh][r] * inv);
      }
    }
  }
}

// ---------------- LayerNorm over last dim (1024) ----------------
__global__ __launch_bounds__(256) void ln_kernel(const float* __restrict__ tmp,
                                                 const float* __restrict__ gamma,
                                                 const float* __restrict__ beta,
                                                 float* __restrict__ out) {
  const int row = blockIdx.x, tid = threadIdx.x;
  const int lane = tid & 63, w = tid >> 6;
  const float* rp = tmp + (size_t)row * 1024;
  float4 v = ((const float4*)rp)[tid];
  float s = v.x + v.y + v.z + v.w;
  float ss = v.x * v.x + v.y * v.y + v.z * v.z + v.w * v.w;
#pragma unroll
  for (int off = 32; off >= 1; off >>= 1) {
    s += __shfl_xor(s, off);
    ss += __shfl_xor(ss, off);
  }
  __shared__ float red[8];
  if (lane == 0) {
    red[w] = s;
    red[4 + w] = ss;
  }
  __syncthreads();
  s = red[0] + red[1] + red[2] + red[3];
  ss = red[4] + red[5] + red[6] + red[7];
  const float mu = s * (1.0f / 1024.0f);
  const float var = ss * (1.0f / 1024.0f) - mu * mu;
  const float rstd = rsqrtf(var + 1e-5f);
  float4 g = ((const float4*)gamma)[tid];
  float4 be = ((const float4*)beta)[tid];
  float4 ov;
  ov.x = (v.x - mu) * rstd * g.x + be.x;
  ov.y = (v.y - mu) * rstd * g.y + be.y;
  ov.z = (v.z - mu) * rstd * g.z + be.z;
  ov.w = (v.w - mu) * rstd * g.w + be.w;
  ((float4*)(out + (size_t)row * 1024))[tid] = ov;
}

extern "C" void kernel_launch(void* const* d_in, const int* in_sizes, int n_in,
                              void* d_out, int out_size, void* d_ws, size_t ws_size,
                              hipStream_t stream) {
  (void)in_sizes; (void)n_in; (void)out_size; (void)ws_size;
  const float* x = (const float*)d_in[0];
  const float* Wq = (const float*)d_in[1];
  const float* Wk = (const float*)d_in[2];
  const float* Wv = (const float*)d_in[3];
  const float* Wo = (const float*)d_in[4];
  const float* bo = (const float*)d_in[5];
  const float* gamma = (const float*)d_in[6];
  const float* beta = (const float*)d_in[7];
  float* out = (float*)d_out;
  char* ws = (char*)d_ws;

  // workspace layout (bytes)
  __hip_bfloat16* xb = (__hip_bfloat16*)(ws + 0);          // 16 MB  [8192][1024]
  __hip_bfloat16* wqkvT = (__hip_bfloat16*)(ws + 16777216);// 6 MB   [3072][1024] (Wq x 0.125*log2e)
  __hip_bfloat16* woT = (__hip_bfloat16*)(ws + 23068672);  // 2 MB
  __hip_bfloat16* Q = (__hip_bfloat16*)(ws + 25165824);    // 16 MB [B,H,S,64]
  __hip_bfloat16* Kt = (__hip_bfloat16*)(ws + 41943040);   // 16 MB [B,H,S,64]
  __hip_bfloat16* Vt = (__hip_bfloat16*)(ws + 58720256);   // 16 MB [B,H,64,S]
  __hip_bfloat16* cc = (__hip_bfloat16*)(ws + 75497472);   // 16 MB [B,S,1024]
  float* tmp = (float*)(ws + 25165824);  // 32 MB fp32, aliases dead Q+Kt (stream-ordered)

  cast_x_kernel<<<8192, 256, 0, stream>>>(x, xb, 2097152);
  // Q scale folds 1/sqrt(64) and log2(e) so flash can use raw v_exp_f32 (exp2)
  qkv_transpose_kernel<<<dim3(16, 1, 48), 256, 0, stream>>>(Wq, Wk, Wv, wqkvT,
                                                            0.125f * 1.44269504088896f);
  transpose_cast_kernel<<<dim3(16, 16, 1), 256, 0, stream>>>(Wo, woT, 1024, 1024, 1.0f);

  // fused QKV projection: Bt = [wqT ; wkT ; wvT] (3072 rows, contiguous)
  gemm128<0><<<dim3(24, 64), 256, 0, stream>>>(xb, wqkvT, Q, Kt, Vt, nullptr, nullptr,
                                               8192, 3072, 1024);

  flash_kernel<<<dim3(64, 32), 128, 0, stream>>>(Q, Kt, Vt, cc);

  gemm128<2><<<dim3(8, 64), 256, 0, stream>>>(cc, woT, tmp, nullptr, nullptr, bo, x,
                                              8192, 1024, 1024);
  ln_kernel<<<8192, 256, 0, stream>>>(tmp, gamma, beta, out);
}

// Round 7
// 315.850 us; speedup vs baseline: 2.8939x; 2.8939x over previous
//
#include <hip/hip_runtime.h>
#include <hip/hip_bf16.h>
#include <stdint.h>

#define DEV __device__ __forceinline__

typedef short s16x8 __attribute__((ext_vector_type(8)));
typedef float f32x4 __attribute__((ext_vector_type(4)));
typedef int i32x4 __attribute__((ext_vector_type(4)));

// async 16B global->LDS. LDS side is wave-uniform base + lane*16 (HW rule).
DEV void async_load16(const void* g, void* l) {
  __builtin_amdgcn_global_load_lds((void __attribute__((address_space(1)))*)(g),
                                   (void __attribute__((address_space(3)))*)(l),
                                   16, 0, 0);
}

DEV unsigned pack_bf16x2(float a, float b) {
  __hip_bfloat162 h = __float22bfloat162_rn(make_float2(a, b));
  union { __hip_bfloat162 h2; unsigned u; } cv;
  cv.h2 = h;
  return cv.u;
}

// ---------------- cast x fp32 -> bf16 ----------------
__global__ __launch_bounds__(256) void cast_x_kernel(const float* __restrict__ in,
                                                     __hip_bfloat16* __restrict__ out, int n4) {
  int i = blockIdx.x * 256 + threadIdx.x;
  if (i >= n4) return;
  float4 v = ((const float4*)in)[i];
  alignas(8) __hip_bfloat16 t[4] = {__float2bfloat16(v.x), __float2bfloat16(v.y),
                                    __float2bfloat16(v.z), __float2bfloat16(v.w)};
  *(uint2*)(out + (size_t)i * 4) = *(const uint2*)t;
}

// ------- transpose-cast: dst[b][c][r] = src[b][r][c] * scale  (bf16 out) -------
// used for Wo (R=C=1024, 256 tiles, scale 1)
__global__ __launch_bounds__(256) void transpose_cast_kernel(const float* __restrict__ src,
                                                             __hip_bfloat16* __restrict__ dst,
                                                             int R, int C, float scale) {
  __shared__ float tile[64][65];
  const int r0 = blockIdx.x * 64, c0 = blockIdx.y * 64, bt = blockIdx.z;
  const int tc = threadIdx.x & 63, tr = threadIdx.x >> 6;
  const float* sp = src + (size_t)bt * R * C;
#pragma unroll
  for (int rr = 0; rr < 64; rr += 4)
    tile[tr + rr][tc] = sp[(size_t)(r0 + tr + rr) * C + c0 + tc];
  __syncthreads();
  __hip_bfloat16* dp = dst + (size_t)bt * R * C;
#pragma unroll
  for (int rr = 0; rr < 64; rr += 4) {
    int cc = tr + rr;
    dp[(size_t)(c0 + cc) * R + r0 + tc] = __float2bfloat16(tile[tc][cc] * scale);
  }
}

// ------- fused Wq/Wk/Wv transpose-cast (R=1024, C=64, 16 heads each) -------
// z = 0..47: which = z>>4 (0=Wq,1=Wk,2=Wv), head = z&15. Wq scaled.
__global__ __launch_bounds__(256) void qkv_transpose_kernel(const float* __restrict__ Wq,
                                                            const float* __restrict__ Wk,
                                                            const float* __restrict__ Wv,
                                                            __hip_bfloat16* __restrict__ dst,
                                                            float qscale) {
  __shared__ float tile[64][65];
  const int z = blockIdx.z, which = z >> 4, bt = z & 15;
  const int r0 = blockIdx.x * 64;
  const int tc = threadIdx.x & 63, tr = threadIdx.x >> 6;
  const float* src = (which == 0) ? Wq : (which == 1) ? Wk : Wv;
  const float scale = (which == 0) ? qscale : 1.0f;
  const float* sp = src + (size_t)bt * 1024 * 64;
#pragma unroll
  for (int rr = 0; rr < 64; rr += 4)
    tile[tr + rr][tc] = sp[(size_t)(r0 + tr + rr) * 64 + tc];
  __syncthreads();
  __hip_bfloat16* dp = dst + (size_t)z * 1024 * 64;
#pragma unroll
  for (int rr = 0; rr < 64; rr += 4) {
    int cc = tr + rr;
    dp[(size_t)(cc)*1024 + r0 + tc] = __float2bfloat16(tile[tc][cc] * scale);
  }
}

// ---------------- 128x128 bf16 MFMA GEMM, BK=32, m97 structure ----------------
// C[M,N] = A[M,K] * Bt[N,K]^T.
// MODE 0 (fused QKV, N=3072): cols <1024 -> Q [B,H,S,DH] (out0), <2048 -> K (out1),
//                             >=2048 -> Vt [B,DHg,S] packed-transposed store (out2)
// MODE 2: fp32 out0 = acc + bias[col] + resid[row*1024+col]
template <int MODE>
__global__ __launch_bounds__(256) void gemm128(const __hip_bfloat16* __restrict__ A,
                                               const __hip_bfloat16* __restrict__ Bt,
                                               void* __restrict__ out0,
                                               void* __restrict__ out1,
                                               void* __restrict__ out2,
                                               const float* __restrict__ bias,
                                               const float* __restrict__ resid,
                                               int M, int N, int K) {
  __shared__ __hip_bfloat16 As[128 * 32];
  __shared__ __hip_bfloat16 Bs[128 * 32];
  const int tid = threadIdx.x;
  const int lane = tid & 63, w = tid >> 6;
  const int lr = lane & 15, lq = lane >> 4;
  const int wm = w >> 1, wn = w & 1;
  const int m0 = blockIdx.y * 128, n0 = blockIdx.x * 128;

  const f32x4 fz = {0.f, 0.f, 0.f, 0.f};
  f32x4 acc[4][4];
#pragma unroll
  for (int i = 0; i < 4; i++)
#pragma unroll
    for (int j = 0; j < 4; j++) acc[i][j] = fz;

  const int kiters = K >> 5;
  for (int kt = 0; kt < kiters; kt++) {
    __syncthreads();
#pragma unroll
    for (int r = 0; r < 2; r++) {
      const int c = r * 256 + tid;
      const int row = c >> 2, kc = c & 3;
      async_load16((const short*)A + (size_t)(m0 + row) * K + kt * 32 + kc * 8,
                   (char*)As + (r * 256 + (tid & 0xC0)) * 16);
      async_load16((const short*)Bt + (size_t)(n0 + row) * K + kt * 32 + kc * 8,
                   (char*)Bs + (r * 256 + (tid & 0xC0)) * 16);
    }
    __syncthreads();
    const short* Ap = (const short*)As;
    const short* Bp = (const short*)Bs;
    s16x8 av[4], bv[4];
#pragma unroll
    for (int i = 0; i < 4; i++)
      av[i] = *(const s16x8*)(Ap + (wm * 64 + i * 16 + lr) * 32 + lq * 8);
#pragma unroll
    for (int j = 0; j < 4; j++)
      bv[j] = *(const s16x8*)(Bp + (wn * 64 + j * 16 + lr) * 32 + lq * 8);
#pragma unroll
    for (int i = 0; i < 4; i++)
#pragma unroll
      for (int j = 0; j < 4; j++)
        acc[i][j] = __builtin_amdgcn_mfma_f32_16x16x32_bf16(av[i], bv[j], acc[i][j], 0, 0, 0);
  }

  if constexpr (MODE == 0) {
    if (n0 < 2048) {
      __hip_bfloat16* dst01 = (__hip_bfloat16*)((n0 < 1024) ? out0 : out1);
#pragma unroll
      for (int i = 0; i < 4; i++)
#pragma unroll
        for (int j = 0; j < 4; j++)
#pragma unroll
          for (int r = 0; r < 4; r++) {
            const int row = m0 + wm * 64 + i * 16 + lq * 4 + r;
            const int col = n0 + wn * 64 + j * 16 + lr;
            const int bb = row >> 11, s = row & 2047;
            const int colq = col & 1023;
            dst01[((((size_t)bb * 16 + (colq >> 6)) * 2048 + s) << 6) + (col & 63)] =
                __float2bfloat16(acc[i][j][r]);
          }
    } else {
      // V block: packed-transpose store to Vt[b][dhg][s] (4 consecutive s per lane)
#pragma unroll
      for (int i = 0; i < 4; i++)
#pragma unroll
        for (int j = 0; j < 4; j++) {
          const int row0 = m0 + wm * 64 + i * 16 + lq * 4;
          const int col = (n0 - 2048) + wn * 64 + j * 16 + lr;  // dh-global 0..1023
          const int bb = row0 >> 11, s0 = row0 & 2047;
          alignas(8) __hip_bfloat16 t4[4] = {
              __float2bfloat16(acc[i][j][0]), __float2bfloat16(acc[i][j][1]),
              __float2bfloat16(acc[i][j][2]), __float2bfloat16(acc[i][j][3])};
          *(uint2*)((__hip_bfloat16*)out2 + (size_t)bb * 2097152 + (size_t)col * 2048 + s0) =
              *(const uint2*)t4;
        }
    }
  } else {
#pragma unroll
    for (int i = 0; i < 4; i++)
#pragma unroll
      for (int j = 0; j < 4; j++)
#pragma unroll
        for (int r = 0; r < 4; r++) {
          const int row = m0 + wm * 64 + i * 16 + lq * 4 + r;
          const int col = n0 + wn * 64 + j * 16 + lr;
          const size_t idx = (size_t)row * 1024 + col;
          ((float*)out0)[idx] = acc[i][j][r] + bias[col] + resid[idx];
        }
  }
}

// ------------- streaming-softmax attention: 2-wave blocks, 64 q/wave -------------
// Q [B,H,S,64] pre-scaled by 0.125*log2(e) -> log2-domain scores, exp2 softmax.
// K [B,H,S,64], Vt [B,H,64,S] -> concat out [B,S,1024].
// Block = 128 threads (2 waves); both waves cover the same 64 q; wave w handles
// the w-th 32-kv half of each staged 64-kv tile. nt=4 (64 q/wave) -> 8
// ds_read_b128 feed 32 MFMAs (0.25 reads/MFMA). One LDS exchange at the end.
// CRITICAL (R6 lesson): accumulator arrays o[]/lsum[] must NEVER be indexed by a
// runtime value (e.g. anything derived from w) — LLVM demotes the array to
// scratch and every MFMA round-trips HBM (3.6GB traffic, 7x slowdown). The
// epilogue therefore uses wave-uniform if(w==0)/else with constant indices only.
// Grid x=hb: XCD = blockid%8 = hb%8 -> all 32 qt of one (b,h) share K/V in one L2.
__global__ __launch_bounds__(128, 3) void flash_kernel(const __hip_bfloat16* __restrict__ Qg,
                                                       const __hip_bfloat16* __restrict__ Kg,
                                                       const __hip_bfloat16* __restrict__ Vtg,
                                                       __hip_bfloat16* __restrict__ Og) {
  __shared__ alignas(16) char smem[16896];  // staging 16KB; epilogue xch 16KB + lx 512B
  __hip_bfloat16* Klds = (__hip_bfloat16*)smem;           // [64 kv][64 d] chunks xor g(kv)
  __hip_bfloat16* Vlds = (__hip_bfloat16*)(smem + 8192);  // [64 dh][64 kv] chunks xor (dh&7)
  float* xch = (float*)smem;                              // 2 slots x 2048 f32
  float* lx = (float*)(smem + 16384);                     // [2][32]
  const int tid = threadIdx.x;
  const int lane = tid & 63, w = tid >> 6;
  const int lr = lane & 15, lq = lane >> 4;
  const int hb = blockIdx.x, qt = blockIdx.y;
  const int h = hb >> 2, b = hb & 3;
  const size_t bh = (size_t)b * 16 + h;
  const short* Qbase = (const short*)Qg + (bh * 2048 + (size_t)qt * 64) * 64;
  const short* Kbh = (const short*)Kg + bh * 2048 * 64;
  const short* Vbh = (const short*)Vtg + bh * 64 * 2048;

  // tile-row->kv permutation pieces (in-lane P trick); gk == g(kvrow) == lr&7
  const int rbase = (lr >> 2) * 8 + (lr & 3);
  const int gk = lr & 7;

  // Q as B-operand fragments: wave holds all 64 q rows of the block (4 n-tiles)
  s16x8 qb[4][2];
#pragma unroll
  for (int nt = 0; nt < 4; nt++)
#pragma unroll
    for (int ks = 0; ks < 2; ks++)
      qb[nt][ks] = *(const s16x8*)(Qbase + (nt * 16 + lr) * 64 + ks * 32 + lq * 8);

  const f32x4 fz = {0.f, 0.f, 0.f, 0.f};
  f32x4 o[4][4];  // [q n-tile][dh n-tile] -- partial over this wave's kv halves
#pragma unroll
  for (int i = 0; i < 4; i++)
#pragma unroll
    for (int j = 0; j < 4; j++) o[i][j] = fz;
  float lsum[4] = {0.f, 0.f, 0.f, 0.f};

  for (int kb = 0; kb < 32; kb++) {  // 64-kv tiles
    __syncthreads();
    const short* Ksrc = Kbh + kb * 64 * 64;
#pragma unroll
    for (int r = 0; r < 4; r++) {  // K tile: 64 rows x 128B, chunk xor g(row)
      int c = r * 128 + tid;
      int row = c >> 3, ck = c & 7;
      int g = (row & 3) | (((row >> 3) & 1) << 2);
      async_load16(Ksrc + row * 64 + (ck ^ g) * 8,
                   (char*)Klds + (r * 128 + (tid & 64)) * 16);
    }
#pragma unroll
    for (int r = 0; r < 4; r++) {  // Vt tile: 64 rows x 128B, chunk xor (row&7)
      int c = r * 128 + tid;
      int row = c >> 3, ck = c & 7;
      async_load16(Vbh + (size_t)row * 2048 + kb * 64 + ((ck ^ (row & 7))) * 8,
                   (char*)Vlds + (r * 128 + (tid & 64)) * 16);
    }
    __syncthreads();

    const short* Kp = (const short*)Klds;
    const short* Vp = (const short*)Vlds;

    // this wave's 32-kv half; S^T = K*Q^T, P built in-lane
    union { i32x4 i; s16x8 s; } pa[4];
#pragma unroll
    for (int mt = 0; mt < 2; mt++) {
      const int kvrow = w * 32 + mt * 4 + rbase;
      s16x8 kf0 = *(const s16x8*)(Kp + kvrow * 64 + (((0 * 4 + lq) ^ gk)) * 8);
      s16x8 kf1 = *(const s16x8*)(Kp + kvrow * 64 + (((1 * 4 + lq) ^ gk)) * 8);
#pragma unroll
      for (int nt = 0; nt < 4; nt++) {
        f32x4 st = fz;
        st = __builtin_amdgcn_mfma_f32_16x16x32_bf16(kf0, qb[nt][0], st, 0, 0, 0);
        st = __builtin_amdgcn_mfma_f32_16x16x32_bf16(kf1, qb[nt][1], st, 0, 0, 0);
        float e0 = __builtin_amdgcn_exp2f(st[0]);
        float e1 = __builtin_amdgcn_exp2f(st[1]);
        float e2 = __builtin_amdgcn_exp2f(st[2]);
        float e3 = __builtin_amdgcn_exp2f(st[3]);
        lsum[nt] += (e0 + e1) + (e2 + e3);
        pa[nt].i[mt * 2 + 0] = (int)pack_bf16x2(e0, e1);
        pa[nt].i[mt * 2 + 1] = (int)pack_bf16x2(e2, e3);
      }
    }
#pragma unroll
    for (int ndh = 0; ndh < 4; ndh++) {
      int vrow = ndh * 16 + lr;
      s16x8 vb = *(const s16x8*)(Vp + vrow * 64 + (((w * 4 + lq) ^ (vrow & 7))) * 8);
#pragma unroll
      for (int nt = 0; nt < 4; nt++)
        o[nt][ndh] = __builtin_amdgcn_mfma_f32_16x16x32_bf16(pa[nt].s, vb, o[nt][ndh], 0, 0, 0);
    }
  }

  // quad-reduce lsum: every lane holds its wave's l(q = nt*16 + lr)
#pragma unroll
  for (int nt = 0; nt < 4; nt++) {
    lsum[nt] += __shfl_xor(lsum[nt], 16);
    lsum[nt] += __shfl_xor(lsum[nt], 32);
  }

  // ---- single lane-linear exchange between the 2 waves ----
  // wave 0 keeps q-tiles {0,1} / ships {2,3}; wave 1 keeps {2,3} / ships {0,1}.
  // ALL indices into o[]/lsum[] below are compile-time constants (see header).
  __syncthreads();
  if (w == 0) {
#pragma unroll
    for (int j = 0; j < 2; j++) {
#pragma unroll
      for (int ndh = 0; ndh < 4; ndh++)
        *(f32x4*)(xch + 0 * 2048 + (j * 4 + ndh) * 256 + lane * 4) = o[2 + j][ndh];
      if (lq == 0) lx[0 * 32 + j * 16 + lr] = lsum[2 + j];
    }
  } else {
#pragma unroll
    for (int j = 0; j < 2; j++) {
#pragma unroll
      for (int ndh = 0; ndh < 4; ndh++)
        *(f32x4*)(xch + 1 * 2048 + (j * 4 + ndh) * 256 + lane * 4) = o[0 + j][ndh];
      if (lq == 0) lx[1 * 32 + j * 16 + lr] = lsum[0 + j];
    }
  }
  __syncthreads();
  if (w == 0) {
#pragma unroll
    for (int j = 0; j < 2; j++) {
#pragma unroll
      for (int ndh = 0; ndh < 4; ndh++)
        o[0 + j][ndh] += *(const f32x4*)(xch + 1 * 2048 + (j * 4 + ndh) * 256 + lane * 4);
      lsum[0 + j] += lx[1 * 32 + j * 16 + lr];
#pragma unroll
      for (int r = 0; r < 4; r++) {
        float lv = __shfl(lsum[0 + j], lq * 4 + r);
        float inv = __builtin_amdgcn_rcpf(lv);
        int rowg = qt * 64 + (0 + j) * 16 + lq * 4 + r;
#pragma unroll
        for (int ndh = 0; ndh < 4; ndh++)
          Og[((size_t)b * 2048 + rowg) * 1024 + h * 64 + ndh * 16 + lr] =
              __float2bfloat16(o[0 + j][ndh][r] * inv);
      }
    }
  } else {
#pragma unroll
    for (int j = 0; j < 2; j++) {
#pragma unroll
      for (int ndh = 0; ndh < 4; ndh++)
        o[2 + j][ndh] += *(const f32x4*)(xch + 0 * 2048 + (j * 4 + ndh) * 256 + lane * 4);
      lsum[2 + j] += lx[0 * 32 + j * 16 + lr];
#pragma unroll
      for (int r = 0; r < 4; r++) {
        float lv = __shfl(lsum[2 + j], lq * 4 + r);
        float inv = __builtin_amdgcn_rcpf(lv);
        int rowg = qt * 64 + (2 + j) * 16 + lq * 4 + r;
#pragma unroll
        for (int ndh = 0; ndh < 4; ndh++)
          Og[((size_t)b * 2048 + rowg) * 1024 + h * 64 + ndh * 16 + lr] =
              __float2bfloat16(o[2 + j][ndh][r] * inv);
      }
    }
  }
}

// ---------------- LayerNorm over last dim (1024) ----------------
__global__ __launch_bounds__(256) void ln_kernel(const float* __restrict__ tmp,
                                                 const float* __restrict__ gamma,
                                                 const float* __restrict__ beta,
                                                 float* __restrict__ out) {
  const int row = blockIdx.x, tid = threadIdx.x;
  const int lane = tid & 63, w = tid >> 6;
  const float* rp = tmp + (size_t)row * 1024;
  float4 v = ((const float4*)rp)[tid];
  float s = v.x + v.y + v.z + v.w;
  float ss = v.x * v.x + v.y * v.y + v.z * v.z + v.w * v.w;
#pragma unroll
  for (int off = 32; off >= 1; off >>= 1) {
    s += __shfl_xor(s, off);
    ss += __shfl_xor(ss, off);
  }
  __shared__ float red[8];
  if (lane == 0) {
    red[w] = s;
    red[4 + w] = ss;
  }
  __syncthreads();
  s = red[0] + red[1] + red[2] + red[3];
  ss = red[4] + red[5] + red[6] + red[7];
  const float mu = s * (1.0f / 1024.0f);
  const float var = ss * (1.0f / 1024.0f) - mu * mu;
  const float rstd = rsqrtf(var + 1e-5f);
  float4 g = ((const float4*)gamma)[tid];
  float4 be = ((const float4*)beta)[tid];
  float4 ov;
  ov.x = (v.x - mu) * rstd * g.x + be.x;
  ov.y = (v.y - mu) * rstd * g.y + be.y;
  ov.z = (v.z - mu) * rstd * g.z + be.z;
  ov.w = (v.w - mu) * rstd * g.w + be.w;
  ((float4*)(out + (size_t)row * 1024))[tid] = ov;
}

extern "C" void kernel_launch(void* const* d_in, const int* in_sizes, int n_in,
                              void* d_out, int out_size, void* d_ws, size_t ws_size,
                              hipStream_t stream) {
  (void)in_sizes; (void)n_in; (void)out_size; (void)ws_size;
  const float* x = (const float*)d_in[0];
  const float* Wq = (const float*)d_in[1];
  const float* Wk = (const float*)d_in[2];
  const float* Wv = (const float*)d_in[3];
  const float* Wo = (const float*)d_in[4];
  const float* bo = (const float*)d_in[5];
  const float* gamma = (const float*)d_in[6];
  const float* beta = (const float*)d_in[7];
  float* out = (float*)d_out;
  char* ws = (char*)d_ws;

  // workspace layout (bytes)
  __hip_bfloat16* xb = (__hip_bfloat16*)(ws + 0);          // 16 MB  [8192][1024]
  __hip_bfloat16* wqkvT = (__hip_bfloat16*)(ws + 16777216);// 6 MB   [3072][1024] (Wq x 0.125*log2e)
  __hip_bfloat16* woT = (__hip_bfloat16*)(ws + 23068672);  // 2 MB
  __hip_bfloat16* Q = (__hip_bfloat16*)(ws + 25165824);    // 16 MB [B,H,S,64]
  __hip_bfloat16* Kt = (__hip_bfloat16*)(ws + 41943040);   // 16 MB [B,H,S,64]
  __hip_bfloat16* Vt = (__hip_bfloat16*)(ws + 58720256);   // 16 MB [B,H,64,S]
  __hip_bfloat16* cc = (__hip_bfloat16*)(ws + 75497472);   // 16 MB [B,S,1024]
  float* tmp = (float*)(ws + 25165824);  // 32 MB fp32, aliases dead Q+Kt (stream-ordered)

  cast_x_kernel<<<8192, 256, 0, stream>>>(x, xb, 2097152);
  // Q scale folds 1/sqrt(64) and log2(e) so flash can use raw v_exp_f32 (exp2)
  qkv_transpose_kernel<<<dim3(16, 1, 48), 256, 0, stream>>>(Wq, Wk, Wv, wqkvT,
                                                            0.125f * 1.44269504088896f);
  transpose_cast_kernel<<<dim3(16, 16, 1), 256, 0, stream>>>(Wo, woT, 1024, 1024, 1.0f);

  // fused QKV projection: Bt = [wqT ; wkT ; wvT] (3072 rows, contiguous)
  gemm128<0><<<dim3(24, 64), 256, 0, stream>>>(xb, wqkvT, Q, Kt, Vt, nullptr, nullptr,
                                               8192, 3072, 1024);

  flash_kernel<<<dim3(64, 32), 128, 0, stream>>>(Q, Kt, Vt, cc);

  gemm128<2><<<dim3(8, 64), 256, 0, stream>>>(cc, woT, tmp, nullptr, nullptr, bo, x,
                                              8192, 1024, 1024);
  ln_kernel<<<8192, 256, 0, stream>>>(tmp, gamma, beta, out);
}